// Round 9
// baseline (263.549 us; speedup 1.0000x reference)
//
#include <hip/hip_runtime.h>

#define LRELU(x) ((x) > 0.0f ? (x) : 0.2f * (x))

typedef short bf16x8 __attribute__((ext_vector_type(8)));
typedef short bf16x4 __attribute__((ext_vector_type(4)));
typedef float f32x4 __attribute__((ext_vector_type(4)));

__device__ __forceinline__ short f2bf(float f) {
  union { float f; unsigned u; } x{f};
  return (short)((x.u + 0x7FFF + ((x.u >> 16) & 1)) >> 16);
}

// ---------------------------------------------------------------------------
// weight repack: w[s][co][ci][tap] fp32 -> wr[s][co][tap*CI+ci] bf16
__global__ __launch_bounds__(256) void k_repack(
    const float* __restrict__ w, unsigned short* __restrict__ wr, int CO, int CI,
    int total) {
  int idx = blockIdx.x * 256 + threadIdx.x;
  if (idx >= total) return;
  int K = CI * 16;
  int k = idx % K;
  int rest = idx / K;
  int co = rest % CO, s = rest / CO;
  int tap = k / CI, ci = k % CI;
  wr[idx] = (unsigned short)f2bf(w[((size_t)(s * CO + co) * CI + ci) * 16 + tap]);
}

// ---------------------------------------------------------------------------
// conv0: img (B,1,128,128) -> x0t NHWC bf16 (B,64*64,64), k4 s2 p1, bias+leaky
__global__ __launch_bounds__(256) void k_conv0(
    const float* __restrict__ img, const float* __restrict__ w0,
    const float* __restrict__ b0, const int* __restrict__ sidx,
    unsigned short* __restrict__ x0t) {
  __shared__ float Ish[4 * 34];
  const int t = threadIdx.x;
  const int b = blockIdx.x;
  const int py = blockIdx.y;  // 0..255
  const int oh = py >> 2, owb = (py & 3) << 4;
  const int s = sidx[b];
  const float* ip = img + (size_t)b * 16384;
  if (t < 136) {
    int r = t / 34, c = t % 34;
    int ih = 2 * oh - 1 + r, iw = 2 * owb - 1 + c;
    Ish[t] = ((unsigned)ih < 128u && (unsigned)iw < 128u) ? ip[ih * 128 + iw] : 0.f;
  }
  const int co = t & 63, ps = t >> 6;
  float wr[16];
  const float* wp = w0 + (s * 64 + co) * 16;
#pragma unroll
  for (int i = 0; i < 16; i++) wr[i] = wp[i];
  float bb = b0[s * 64 + co];
  __syncthreads();
  unsigned short* op = x0t + ((size_t)b * 4096 + oh * 64 + owb) * 64 + co;
#pragma unroll
  for (int j = 0; j < 4; j++) {
    int pl = ps * 4 + j;
    float acc = bb;
#pragma unroll
    for (int kh = 0; kh < 4; kh++)
#pragma unroll
      for (int kw = 0; kw < 4; kw++)
        acc += wr[kh * 4 + kw] * Ish[kh * 34 + pl * 2 + kw];
    acc = LRELU(acc);
    op[pl * 64] = (unsigned short)f2bf(acc);
  }
}

// ---------------------------------------------------------------------------
// Barrier-free MFMA implicit-GEMM k4s2p1 conv: A (packed bf16 weights) and
// B (NHWC bf16 activations) fragments loaded directly from global per lane.
// No LDS, no __syncthreads in the K-loop. grid (B, COT*NT, Z) with Z K-split.
template <int CI, int CO, int HIN, int OWSHIFT>
__global__ __launch_bounds__(256) void k_conv_dir(
    const unsigned short* __restrict__ xt, const unsigned short* __restrict__ wr,
    const int* __restrict__ sidx, float* __restrict__ out0, float* __restrict__ out1) {
  constexpr int WIN = HIN;
  constexpr int OW = 1 << OWSHIFT;
  constexpr int OH = HIN / 2;
  constexpr int NPB = OH * OW;
  constexpr int NT = NPB / 64;
  constexpr int CPT = CI / 32;  // 32-k chunks per tap
  const int t = threadIdx.x;
  const int b = blockIdx.x;
  const int co0 = (blockIdx.y / NT) * 64;
  const int n0 = (blockIdx.y % NT) * 64;
  const int nkc = (CI / 2) / gridDim.z;
  const int kcb = blockIdx.z * nkc;
  float* dst = blockIdx.z ? out1 : out0;
  const int s = sidx[b];
  const int lane = t & 63, wv = t >> 6;
  const int wm = (wv >> 1) * 32, wn = (wv & 1) * 32;
  const int quad = lane >> 4, l16 = lane & 15;

  const unsigned short* aptr0 =
      wr + (size_t)(s * CO + co0 + wm + l16) * (CI * 16) + quad * 8;
  const unsigned short* aptr1 = aptr0 + (size_t)16 * (CI * 16);
  const unsigned short* xb = xt + (size_t)b * (HIN * WIN) * CI;
  int ihb[2], iwb[2];
#pragma unroll
  for (int j = 0; j < 2; j++) {
    int p = n0 + wn + j * 16 + l16;
    int oh = p >> OWSHIFT, ow = p & (OW - 1);
    ihb[j] = 2 * oh - 1;
    iwb[j] = 2 * ow - 1;
  }

  f32x4 acc[2][2];
#pragma unroll
  for (int i = 0; i < 2; i++)
#pragma unroll
    for (int j = 0; j < 2; j++) acc[i][j] = (f32x4){0.f, 0.f, 0.f, 0.f};

#pragma unroll 4
  for (int kk = 0; kk < nkc; kk++) {
    int kc = kcb + kk;
    int tap = kc / CPT;
    int cio = (kc % CPT) * 32 + quad * 8;
    int kh = tap >> 2, kw = tap & 3;
    bf16x8 af0 = *(const bf16x8*)(aptr0 + kc * 32);
    bf16x8 af1 = *(const bf16x8*)(aptr1 + kc * 32);
    bf16x8 bfv[2];
#pragma unroll
    for (int j = 0; j < 2; j++) {
      int ih = ihb[j] + kh, iw = iwb[j] + kw;
      bf16x8 bv = {0, 0, 0, 0, 0, 0, 0, 0};
      if ((unsigned)ih < (unsigned)HIN && (unsigned)iw < (unsigned)WIN)
        bv = *(const bf16x8*)(xb + ((size_t)(ih * WIN + iw)) * CI + cio);
      bfv[j] = bv;
    }
#pragma unroll
    for (int j = 0; j < 2; j++) {
      acc[0][j] = __builtin_amdgcn_mfma_f32_16x16x32_bf16(af0, bfv[j], acc[0][j], 0, 0, 0);
      acc[1][j] = __builtin_amdgcn_mfma_f32_16x16x32_bf16(af1, bfv[j], acc[1][j], 0, 0, 0);
    }
  }
#pragma unroll
  for (int i = 0; i < 2; i++) {
    int cobase = co0 + wm + i * 16 + quad * 4;
#pragma unroll
    for (int j = 0; j < 2; j++) {
      int n = n0 + wn + j * 16 + l16;
#pragma unroll
      for (int r = 0; r < 4; r++)
        dst[((size_t)b * CO + cobase + r) * NPB + n] = acc[i][j][r];
    }
  }
}

// ---------------------------------------------------------------------------
// fused sum + instance norm (+leaky): o = lrelu(inorm(a+b)); block per (b,c)
template <int NPIX>
__global__ __launch_bounds__(256) void k_inorm2(
    const float* __restrict__ a, const float* __restrict__ b, float* __restrict__ o) {
  constexpr int E = NPIX / 256;
  size_t base = (size_t)blockIdx.x * NPIX;
  const int t = threadIdx.x;
  float v[E];
  float sum = 0.f, sq = 0.f;
#pragma unroll
  for (int i = 0; i < E; i++) {
    size_t idx = base + i * 256 + t;
    v[i] = a[idx] + b[idx];
    sum += v[i];
    sq += v[i] * v[i];
  }
#pragma unroll
  for (int off = 32; off > 0; off >>= 1) {
    sum += __shfl_down(sum, off, 64);
    sq += __shfl_down(sq, off, 64);
  }
  __shared__ float red[8];
  int wid = t >> 6;
  if ((t & 63) == 0) {
    red[wid] = sum;
    red[4 + wid] = sq;
  }
  __syncthreads();
  float S = red[0] + red[1] + red[2] + red[3];
  float SQ = red[4] + red[5] + red[6] + red[7];
  float m = S * (1.0f / NPIX);
  float var = SQ * (1.0f / NPIX) - m * m;
  float inv = rsqrtf(var + 1e-5f);
#pragma unroll
  for (int i = 0; i < E; i++) {
    float r = (v[i] - m) * inv;
    o[base + i * 256 + t] = LRELU(r);
  }
}

// ---------------------------------------------------------------------------
// fused q+k 1x1 conv (CO=16 each): grid (B, 8); y<4 -> q tile, else k tile
__global__ __launch_bounds__(256) void k_proj_qk(
    const float* __restrict__ xin, const float* __restrict__ wq,
    const float* __restrict__ bq, const float* __restrict__ wk,
    const float* __restrict__ bk, const int* __restrict__ sidx,
    float* __restrict__ q, float* __restrict__ kout) {
  __shared__ float xsh[32 * 256];
  __shared__ float wsh[16 * 32];
  const int t = threadIdx.x;
  const int b = blockIdx.x;
  const int sel = blockIdx.y >> 2, nw = blockIdx.y & 3;
  const float* w = sel ? wk : wq;
  const float* bias = sel ? bk : bq;
  float* out = sel ? kout : q;
  const int nn0 = nw * 256;
  const int s = sidx[b];
  const int cg = t >> 6, ng = t & 63;
  const float* xb = xin + (size_t)b * 128 * 1024;
  float4 acc4[4];
#pragma unroll
  for (int c = 0; c < 4; c++) {
    float bb = bias[s * 16 + cg * 4 + c];
    acc4[c] = make_float4(bb, bb, bb, bb);
  }
  for (int cc = 0; cc < 4; cc++) {
#pragma unroll
    for (int k = 0; k < 8; k++) {
      int id = t + (k << 8);
      int ci = id >> 6, nf = id & 63;
      ((float4*)xsh)[id] = ((const float4*)(xb + (cc * 32 + ci) * 1024 + nn0))[nf];
    }
    if (t < 128)
      ((float4*)wsh)[t] =
          ((const float4*)(w + ((size_t)(s * 16 + (t >> 3))) * 128 + cc * 32))[t & 7];
    __syncthreads();
#pragma unroll
    for (int ci4 = 0; ci4 < 8; ci4++) {
      float4 wv[4], xv[4];
#pragma unroll
      for (int c = 0; c < 4; c++) wv[c] = ((const float4*)wsh)[(cg * 4 + c) * 8 + ci4];
#pragma unroll
      for (int i = 0; i < 4; i++) xv[i] = ((const float4*)xsh)[(ci4 * 4 + i) * 64 + ng];
#pragma unroll
      for (int c = 0; c < 4; c++)
#pragma unroll
        for (int i = 0; i < 4; i++) {
          float wvc = i == 0 ? wv[c].x : i == 1 ? wv[c].y : i == 2 ? wv[c].z : wv[c].w;
          acc4[c].x += wvc * xv[i].x;
          acc4[c].y += wvc * xv[i].y;
          acc4[c].z += wvc * xv[i].z;
          acc4[c].w += wvc * xv[i].w;
        }
    }
    __syncthreads();
  }
#pragma unroll
  for (int c = 0; c < 4; c++) {
    int co = cg * 4 + c;
    ((float4*)(out + ((size_t)b * 16 + co) * 1024 + nn0))[ng] = acc4[c];
  }
}

// ---------------------------------------------------------------------------
// v projection writing bf16 in MFMA-chunked layout vpk[b][m/32][co][m%32]
__global__ __launch_bounds__(256) void k_proj_v(
    const float* __restrict__ xin, const float* __restrict__ w,
    const float* __restrict__ bias, const int* __restrict__ sidx,
    unsigned short* __restrict__ out) {
  __shared__ float xsh[32 * 256];
  __shared__ float wsh[16 * 32];
  const int t = threadIdx.x;
  const int b = blockIdx.x;
  const int cow = blockIdx.y >> 2, nw = blockIdx.y & 3;
  const int co0 = cow * 16, nn0 = nw * 256;
  const int s = sidx[b];
  const int cg = t >> 6, ng = t & 63;
  const float* xb = xin + (size_t)b * 128 * 1024;
  float4 acc4[4];
#pragma unroll
  for (int c = 0; c < 4; c++) {
    float bb = bias[s * 128 + co0 + cg * 4 + c];
    acc4[c] = make_float4(bb, bb, bb, bb);
  }
  for (int cc = 0; cc < 4; cc++) {
#pragma unroll
    for (int k = 0; k < 8; k++) {
      int id = t + (k << 8);
      int ci = id >> 6, nf = id & 63;
      ((float4*)xsh)[id] = ((const float4*)(xb + (cc * 32 + ci) * 1024 + nn0))[nf];
    }
    if (t < 128)
      ((float4*)wsh)[t] =
          ((const float4*)(w + ((size_t)(s * 128 + co0 + (t >> 3))) * 128 + cc * 32))[t & 7];
    __syncthreads();
#pragma unroll
    for (int ci4 = 0; ci4 < 8; ci4++) {
      float4 wv[4], xv[4];
#pragma unroll
      for (int c = 0; c < 4; c++) wv[c] = ((const float4*)wsh)[(cg * 4 + c) * 8 + ci4];
#pragma unroll
      for (int i = 0; i < 4; i++) xv[i] = ((const float4*)xsh)[(ci4 * 4 + i) * 64 + ng];
#pragma unroll
      for (int c = 0; c < 4; c++)
#pragma unroll
        for (int i = 0; i < 4; i++) {
          float wvc = i == 0 ? wv[c].x : i == 1 ? wv[c].y : i == 2 ? wv[c].z : wv[c].w;
          acc4[c].x += wvc * xv[i].x;
          acc4[c].y += wvc * xv[i].y;
          acc4[c].z += wvc * xv[i].z;
          acc4[c].w += wvc * xv[i].w;
        }
    }
    __syncthreads();
  }
  int n = nn0 + ng * 4;
#pragma unroll
  for (int c = 0; c < 4; c++) {
    int co = co0 + cg * 4 + c;
    bf16x4 u;
    u[0] = f2bf(acc4[c].x);
    u[1] = f2bf(acc4[c].y);
    u[2] = f2bf(acc4[c].z);
    u[3] = f2bf(acc4[c].w);
    *(bf16x4*)(out + (((size_t)b * 32 + (n >> 5)) * 128 + co) * 32 + (n & 31)) = u;
  }
}

// ---------------------------------------------------------------------------
// fused self-attention, MFMA PV (coalesced chunked V), barrier-free K-loop,
// LDS-transposed epilogue (coalesced residual read + ybf NHWC write).
__global__ __launch_bounds__(256) void k_attn(
    const float* __restrict__ q, const float* __restrict__ k,
    const unsigned short* __restrict__ vpk, const float* __restrict__ x1,
    const float* __restrict__ gamma, const int* __restrict__ sidx,
    unsigned short* __restrict__ ybf) {
  __shared__ __align__(16) short Psh[16 * 1032];  // 33 KB; reused as Osh/Osh2
  __shared__ float qsh[256];
  __shared__ float redm[64], reds[64];
  const int t = threadIdx.x;
  const int b = blockIdx.x >> 6;
  const int n0 = (blockIdx.x & 63) << 4;
  const int lane = t & 63, wv = t >> 6;
  const int quad = lane >> 4, l16 = lane & 15;
  const float* qb = q + (size_t)b * 16 * 1024;
  const float* kb = k + (size_t)b * 16 * 1024;
  const float* xb = x1 + (size_t)b * 128 * 1024;

  qsh[t] = qb[((t >> 4) << 10) + n0 + (t & 15)];
  __syncthreads();

  // ---- scores: thread handles m = 4t..4t+3, all 16 nl
  float acc[4][16];
#pragma unroll
  for (int j = 0; j < 4; j++)
#pragma unroll
    for (int nl = 0; nl < 16; nl++) acc[j][nl] = 0.0f;
#pragma unroll
  for (int c = 0; c < 16; c++) {
    float4 kv = *(const float4*)(kb + (c << 10) + 4 * t);
    const float* qr = qsh + c * 16;
#pragma unroll
    for (int j = 0; j < 4; j++) {
      float kk = j == 0 ? kv.x : j == 1 ? kv.y : j == 2 ? kv.z : kv.w;
#pragma unroll
      for (int nl = 0; nl < 16; nl++) acc[j][nl] += kk * qr[nl];
    }
  }
  float lmax[16];
#pragma unroll
  for (int nl = 0; nl < 16; nl++)
    lmax[nl] = fmaxf(fmaxf(acc[0][nl], acc[1][nl]), fmaxf(acc[2][nl], acc[3][nl]));
#pragma unroll
  for (int o = 32; o > 0; o >>= 1)
#pragma unroll
    for (int nl = 0; nl < 16; nl++) lmax[nl] = fmaxf(lmax[nl], __shfl_xor(lmax[nl], o, 64));
  if (lane == 0)
#pragma unroll
    for (int nl = 0; nl < 16; nl++) redm[wv * 16 + nl] = lmax[nl];
  __syncthreads();
#pragma unroll
  for (int nl = 0; nl < 16; nl++)
    lmax[nl] = fmaxf(fmaxf(redm[nl], redm[16 + nl]), fmaxf(redm[32 + nl], redm[48 + nl]));
  float lsum[16];
#pragma unroll
  for (int nl = 0; nl < 16; nl++) lsum[nl] = 0.0f;
#pragma unroll
  for (int j = 0; j < 4; j++)
#pragma unroll
    for (int nl = 0; nl < 16; nl++) {
      float e = __expf(acc[j][nl] - lmax[nl]);
      acc[j][nl] = e;
      lsum[nl] += e;
    }
#pragma unroll
  for (int o = 32; o > 0; o >>= 1)
#pragma unroll
    for (int nl = 0; nl < 16; nl++) lsum[nl] += __shfl_xor(lsum[nl], o, 64);
  if (lane == 0)
#pragma unroll
    for (int nl = 0; nl < 16; nl++) reds[wv * 16 + nl] = lsum[nl];
#pragma unroll
  for (int nl = 0; nl < 16; nl++) {
    bf16x4 pv;
    pv[0] = f2bf(acc[0][nl]);
    pv[1] = f2bf(acc[1][nl]);
    pv[2] = f2bf(acc[2][nl]);
    pv[3] = f2bf(acc[3][nl]);
    *(bf16x4*)&Psh[nl * 1032 + 4 * t] = pv;
  }
  __syncthreads();

  // ---- PV: barrier-free, fully coalesced V loads (chunked layout)
  const unsigned short* vp =
      vpk + ((size_t)b * 32 * 128 + (size_t)(wv * 32 + l16)) * 32 + quad * 8;
  const short* prow = Psh + l16 * 1032 + quad * 8;
  f32x4 dacc[2];
  dacc[0] = (f32x4){0.f, 0.f, 0.f, 0.f};
  dacc[1] = (f32x4){0.f, 0.f, 0.f, 0.f};
#pragma unroll 8
  for (int mt = 0; mt < 32; mt++) {
    bf16x8 af0 = *(const bf16x8*)(vp + mt * 4096);
    bf16x8 af1 = *(const bf16x8*)(vp + 512 + mt * 4096);
    bf16x8 bfr = *(const bf16x8*)(prow + mt * 32);
    dacc[0] = __builtin_amdgcn_mfma_f32_16x16x32_bf16(af0, bfr, dacc[0], 0, 0, 0);
    dacc[1] = __builtin_amdgcn_mfma_f32_16x16x32_bf16(af1, bfr, dacc[1], 0, 0, 0);
  }
  __syncthreads();  // all waves done reading Psh

  // ---- epilogue via LDS transpose (alias into Psh)
  float* Osh = (float*)Psh;          // [128][17] fp32 (8704 B)
  short* Osh2 = Psh + 4352;          // [16][136] bf16 (4352 B), 16B-aligned
#pragma unroll
  for (int i = 0; i < 2; i++) {
    int cob = wv * 32 + i * 16 + quad * 4;
#pragma unroll
    for (int r = 0; r < 4; r++) Osh[(cob + r) * 17 + l16] = dacc[i][r];
  }
  __syncthreads();
  float g = gamma[sidx[b]];
  {
    // pass A (co-major): coalesced x1 reads
    int co = t >> 1, j0 = (t & 1) * 8;
    const float* xr = xb + (co << 10) + n0 + j0;
    float4 xv0 = *(const float4*)xr;
    float4 xv1 = *(const float4*)(xr + 4);
    float xs[8] = {xv0.x, xv0.y, xv0.z, xv0.w, xv1.x, xv1.y, xv1.z, xv1.w};
#pragma unroll
    for (int j = 0; j < 8; j++) {
      int nl = j0 + j;
      float rs = 1.0f / (reds[nl] + reds[16 + nl] + reds[32 + nl] + reds[48 + nl]);
      Osh2[nl * 136 + co] = f2bf(g * Osh[co * 17 + nl] * rs + xs[j]);
    }
  }
  __syncthreads();
  {
    // pass B (n-major): coalesced ybf writes
    int nl = t >> 4, cg = t & 15;
    bf16x8 u = *(const bf16x8*)&Osh2[nl * 136 + cg * 8];
    *(bf16x8*)(ybf + ((size_t)b * 1024 + n0 + nl) * 128 + cg * 8) = u;
  }
}

// ---------------------------------------------------------------------------
// head: init out with bias, then partial conv via LDS + atomicAdd
__global__ __launch_bounds__(256) void k_head_init(
    const float* __restrict__ bh, const int* __restrict__ sidx, float* __restrict__ out) {
  int i = blockIdx.x * 256 + threadIdx.x;
  if (i < 3600) out[i] = bh[sidx[i / 225]];
}

__global__ __launch_bounds__(256) void k_head_part(
    const float* __restrict__ x2, const float* __restrict__ wh,
    const int* __restrict__ sidx, float* __restrict__ out) {
  __shared__ float Xs[32 * 256];
  __shared__ float Wsh[512];
  const int t = threadIdx.x;
  const int b = blockIdx.x, cc = blockIdx.y;
  const int s = sidx[b];
  const float* xp = x2 + ((size_t)b * 256 + cc * 32) * 256;
#pragma unroll
  for (int i = 0; i < 32; i++) Xs[i * 256 + t] = xp[i * 256 + t];
#pragma unroll
  for (int i = 0; i < 2; i++) {
    int idx = i * 256 + t;
    Wsh[idx] = wh[s * 4096 + cc * 512 + idx];
  }
  __syncthreads();
  if (t < 225) {
    int oh = t / 15, ow = t % 15;
    float acc = 0.0f;
    for (int ci = 0; ci < 32; ci++) {
      const float* xr = Xs + ci * 256;
      const float* wr = Wsh + ci * 16;
#pragma unroll
      for (int kh = 0; kh < 4; kh++) {
        int ih = oh - 1 + kh;
        if ((unsigned)ih >= 16u) continue;
#pragma unroll
        for (int kw = 0; kw < 4; kw++) {
          int iw = ow - 1 + kw;
          if ((unsigned)iw >= 16u) continue;
          acc += wr[kh * 4 + kw] * xr[(ih << 4) + iw];
        }
      }
    }
    atomicAdd(out + b * 225 + t, acc);
  }
}

// ---------------------------------------------------------------------------
extern "C" void kernel_launch(void* const* d_in, const int* in_sizes, int n_in,
                              void* d_out, int out_size, void* d_ws, size_t ws_size,
                              hipStream_t stream) {
  const float* img = (const float*)d_in[0];
  const int* sidx = (const int*)d_in[1];
  const float* w0 = (const float*)d_in[2];
  const float* b0 = (const float*)d_in[3];
  const float* w1 = (const float*)d_in[4];
  const float* w2 = (const float*)d_in[6];
  const float* wq = (const float*)d_in[8];
  const float* bq = (const float*)d_in[9];
  const float* wk = (const float*)d_in[10];
  const float* bk = (const float*)d_in[11];
  const float* wv = (const float*)d_in[12];
  const float* bv = (const float*)d_in[13];
  const float* gamma = (const float*)d_in[14];
  const float* wh = (const float*)d_in[15];
  const float* bh = (const float*)d_in[16];
  float* out = (float*)d_out;

  float* ws = (float*)d_ws;
  // float-offset layout (37 MB total, aliased over dead ranges)
  unsigned short* x0t = (unsigned short*)(ws);            // [0,2M) dead after conv1
  float* x1a = ws + 2097152;                              // [2M,4M) dead after inorm
  float* x1b = ws + 4194304;                              // [4M,6M) dead after inorm
  float* x1 = ws + 6291456;                               // [6M,8M)
  float* q = ws + 0;                                      // [0,256K)  (x0t dead)
  float* k = ws + 262144;                                 // [256K,512K)
  unsigned short* vpk = (unsigned short*)(ws + 524288);   // [512K,1.5M)
  unsigned short* ybf = (unsigned short*)(ws + 2097152);  // [2M,3M)  (x1a dead)
  float* x2a = ws + 4194304;                              // [4M,5M)  (x1b dead)
  float* x2b = ws + 5242880;                              // [5M,6M)
  unsigned short* wr1 = (unsigned short*)(ws + 8388608);  // [8M,8.25M)
  unsigned short* wr2 = (unsigned short*)(ws + 8650752);  // [8.25M,9.25M)

  const int B = 16;

  k_repack<<<2048, 256, 0, stream>>>(w1, wr1, 128, 64, 524288);
  k_repack<<<8192, 256, 0, stream>>>(w2, wr2, 256, 128, 2097152);
  k_conv0<<<dim3(B, 256), 256, 0, stream>>>(img, w0, b0, sidx, x0t);
  k_conv_dir<64, 128, 64, 5><<<dim3(B, 32, 2), 256, 0, stream>>>(x0t, wr1, sidx, x1a, x1b);
  k_inorm2<1024><<<B * 128, 256, 0, stream>>>(x1a, x1b, x1);
  k_proj_qk<<<dim3(B, 8), 256, 0, stream>>>(x1, wq, bq, wk, bk, sidx, q, k);
  k_proj_v<<<dim3(B, 32), 256, 0, stream>>>(x1, wv, bv, sidx, vpk);
  k_attn<<<B * 64, 256, 0, stream>>>(q, k, vpk, x1, gamma, sidx, ybf);
  k_conv_dir<128, 256, 32, 4><<<dim3(B, 16, 2), 256, 0, stream>>>(ybf, wr2, sidx, x2a, x2b);
  k_inorm2<256><<<B * 256, 256, 0, stream>>>(x2a, x2b, x2a);
  k_head_init<<<15, 256, 0, stream>>>(bh, sidx, out);
  k_head_part<<<dim3(B, 8), 256, 0, stream>>>(x2a, wh, sidx, out);
}